// Round 1
// 316.683 us; speedup vs baseline: 1.0591x; 1.0591x over previous
//
#include <hip/hip_runtime.h>

// ---------------------------------------------------------------------------
// AttentionMulti: x[4,2048,1024] fp32 -> qkv -> 16-head attention (D=64,
// scale=0.5, key-mask) -> out proj.  Inputs/outputs fp32, mask int32.
// Internal compute in bf16 MFMA.
// ---------------------------------------------------------------------------

typedef __bf16 bf16;
typedef __attribute__((ext_vector_type(8))) __bf16 bf16x8;
typedef __attribute__((ext_vector_type(4))) float f32x4;

#define MFMA16(a, b, c) __builtin_amdgcn_mfma_f32_16x16x32_bf16(a, b, c, 0, 0, 0)
#define GLOAD_LDS(src, dst) __builtin_amdgcn_global_load_lds( \
    (const __attribute__((address_space(1))) void*)(src),     \
    (__attribute__((address_space(3))) void*)(dst), 16, 0, 0)

// 0.5 * log2(e): folded into Q (w_qkv cols 0..1023 and b_qkv[0..1023])
#define QSCALE 0.72134752f

// ---------------------------------------------------------------------------
__global__ __launch_bounds__(256, 1) void cvt_f32_bf16(
    const float* __restrict__ in, bf16* __restrict__ out, int n4)
{
    int i = blockIdx.x * 256 + threadIdx.x;
    if (i >= n4) return;
    float4 v = *(const float4*)(in + (size_t)i * 4);
    union { ushort4 u; bf16 h[4]; } o;
    o.h[0] = (bf16)v.x; o.h[1] = (bf16)v.y; o.h[2] = (bf16)v.z; o.h[3] = (bf16)v.w;
    *(ushort4*)(out + (size_t)i * 4) = o.u;
}

// ---------------------------------------------------------------------------
// out[c][r] = in[r][c] * (c < scale_rows ? scale : 1)
// ---------------------------------------------------------------------------
__global__ __launch_bounds__(256, 1) void transpose_f32_bf16(
    const float* __restrict__ in, bf16* __restrict__ out, int R, int C,
    int scale_rows, float scale)
{
    __shared__ float s[64][65];
    const int t  = threadIdx.x;
    const int r0 = blockIdx.y * 64;
    const int c0 = blockIdx.x * 64;
    const int tr  = t >> 4;
    const int tc4 = (t & 15) * 4;
#pragma unroll
    for (int p = 0; p < 4; ++p) {
        int r = tr + p * 16;
        float4 v = *(const float4*)(in + (size_t)(r0 + r) * C + c0 + tc4);
        s[r][tc4 + 0] = v.x; s[r][tc4 + 1] = v.y;
        s[r][tc4 + 2] = v.z; s[r][tc4 + 3] = v.w;
    }
    __syncthreads();
    const int cw  = t >> 3;
    const int rw8 = (t & 7) * 8;
#pragma unroll
    for (int p = 0; p < 2; ++p) {
        int c = cw + p * 32;
        float f = (c0 + c) < scale_rows ? scale : 1.0f;
        union { uint4 v; bf16 h[8]; } u;
#pragma unroll
        for (int j = 0; j < 8; ++j) u.h[j] = (bf16)(s[rw8 + j][c] * f);
        *(uint4*)(out + (size_t)(c0 + c) * R + r0 + rw8) = u.v;
    }
}

// ---------------------------------------------------------------------------
// C[M][N] = A[M][K] @ Bt[N][K]^T + bias[N] (bias[n] *= qscale for n < qcols)
// ---------------------------------------------------------------------------
template <typename OutT>
__global__ __launch_bounds__(256, 1) void gemm_bias_kernel(
    const bf16* __restrict__ A, const bf16* __restrict__ Bt,
    const float* __restrict__ bias, OutT* __restrict__ C,
    int M, int N, int K, int qcols, float qscale)
{
    __shared__ __align__(16) bf16 As[128 * 32];
    __shared__ __align__(16) bf16 Bs[128 * 32];
    const int t    = threadIdx.x;
    const int lane = t & 63;
    const int wave = t >> 6;
    const int l15  = lane & 15;
    const int g    = lane >> 4;
    const int m0   = blockIdx.y * 128;
    const int n0   = blockIdx.x * 128;
    const int wr   = (wave >> 1) * 64;
    const int wc   = (wave & 1) * 64;

    const f32x4 z = {0.f, 0.f, 0.f, 0.f};
    f32x4 acc[4][4];
#pragma unroll
    for (int i = 0; i < 4; ++i)
#pragma unroll
        for (int j = 0; j < 4; ++j) acc[i][j] = z;

    const int e0 = t * 8;

    for (int k0 = 0; k0 < K; k0 += 32) {
        __syncthreads();
#pragma unroll
        for (int rnd = 0; rnd < 2; ++rnd) {
            int e   = e0 + rnd * 2048;
            int row = e >> 5;
            int col = e & 31;
            GLOAD_LDS(A  + (size_t)(m0 + row) * K + k0 + col, As + e);
            GLOAD_LDS(Bt + (size_t)(n0 + row) * K + k0 + col, Bs + e);
        }
        asm volatile("s_waitcnt vmcnt(0)" ::: "memory");
        __syncthreads();

        bf16x8 a[4], b[4];
#pragma unroll
        for (int i = 0; i < 4; ++i)
            a[i] = *(const bf16x8*)(As + (wr + i * 16 + l15) * 32 + g * 8);
#pragma unroll
        for (int j = 0; j < 4; ++j)
            b[j] = *(const bf16x8*)(Bs + (wc + j * 16 + l15) * 32 + g * 8);
#pragma unroll
        for (int i = 0; i < 4; ++i)
#pragma unroll
            for (int j = 0; j < 4; ++j)
                acc[i][j] = MFMA16(a[i], b[j], acc[i][j]);
    }

#pragma unroll
    for (int i = 0; i < 4; ++i) {
#pragma unroll
        for (int j = 0; j < 4; ++j) {
#pragma unroll
            for (int r = 0; r < 4; ++r) {
                int row = m0 + wr + i * 16 + g * 4 + r;
                int col = n0 + wc + j * 16 + l15;
                float bs = bias[col];
                if (col < qcols) bs *= qscale;
                float v = acc[i][j][r] + bs;
                C[(size_t)row * N + col] = (OutT)v;
            }
        }
    }
}

// ---------------------------------------------------------------------------
// Global V transpose: qkvb V block [b,n][h,d] -> VtG[b][h][d][n]  (bf16)
// f32 LDS tile [64][65]: both scatter phases land ~2 lanes/bank (free).
// ---------------------------------------------------------------------------
__global__ __launch_bounds__(256, 1) void vtrans_kernel(
    const bf16* __restrict__ qkv, bf16* __restrict__ vtg)
{
    __shared__ float tile[64][65];
    const int t  = threadIdx.x;
    const int n0 = blockIdx.x * 64;
    const int bh = blockIdx.y;
    const int b  = bh >> 4, h = bh & 15;
    const bf16* src = qkv + (size_t)(b * 2048 + n0) * 3072 + 2048 + h * 64;
#pragma unroll
    for (int r = 0; r < 2; ++r) {
        int s = t + r * 256;
        int row = s >> 3, c8 = (s & 7) * 8;
        union { uint4 v; bf16 h8[8]; } u;
        u.v = *(const uint4*)(src + (size_t)row * 3072 + c8);
#pragma unroll
        for (int j = 0; j < 8; ++j) tile[row][c8 + j] = (float)u.h8[j];
    }
    __syncthreads();
    bf16* dst = vtg + (size_t)bh * (64 * 2048) + n0;
#pragma unroll
    for (int r = 0; r < 2; ++r) {
        int s = t + r * 256;
        int d = s >> 3, n8 = (s & 7) * 8;
        union { uint4 v; bf16 h8[8]; } o;
#pragma unroll
        for (int j = 0; j < 8; ++j) o.h8[j] = (bf16)tile[n8 + j][d];
        *(uint4*)(dst + (size_t)d * 2048 + n8) = o.v;
    }
}

// ---------------------------------------------------------------------------
// Attention v5:
//  - K AND V staged via global_load_lds width-16 (linear LDS dest,
//    pre-swizzled global source: 8-elem block xor (row&7)) -> no reg
//    round-trip, no in-kernel V transpose, no b128 LDS staging writes.
//  - Mask folded into the MFMA C-init (0 / -1e30); exp2 underflows masked
//    P to exact 0; denominator = mfma(P, ones). V is unmasked.
//  - Q pre-scaled by 0.5*log2e upstream -> exp2(S) directly.
//  - bv fragments read ONCE per chunk, shared by both q-tiles.
//  - Ps row stride 88 (44 words == 12 mod 32): conflict-free b128 reads,
//    16-B aligned (stride-80 was the 4-way / 8.4M-conflict source).
//  - XCD swizzle: 16 q-tile blocks of one (b,h) on one XCD (K/V L2 reuse).
// ---------------------------------------------------------------------------
__global__ __launch_bounds__(256, 3) void attn_kernel(
    const bf16* __restrict__ qkv, const bf16* __restrict__ vtg,
    const int* __restrict__ mask, bf16* __restrict__ O)
{
    __shared__ __align__(16) bf16 Ks[2][64 * 64];   // 16 KB [key][d]  xor-swz
    __shared__ __align__(16) bf16 Vt[2][64 * 64];   // 16 KB [d][key]  xor-swz
    __shared__ __align__(16) bf16 Ps[4][16 * 88];   // 11 KB per-wave P
    __shared__ float mneg[2048];                    //  8 KB: 0 or -1e30

    const int t    = threadIdx.x;
    const int lane = t & 63;
    const int wave = t >> 6;
    const int l15  = lane & 15;
    const int g    = lane >> 4;

    // XCD-aware swizzle (1024 = 8*128, bijective)
    const int bid = (blockIdx.x & 7) * 128 + (blockIdx.x >> 3);
    const int qt  = bid & 15;
    const int bh  = bid >> 4;
    const int h   = bh & 15;
    const int b   = bh >> 4;
    const int q0  = qt * 128 + wave * 16;           // tile0; tile1 = q0 + 64

    const int* mrow = mask + b * 2048;
    for (int i = t; i < 2048; i += 256)
        mneg[i] = mrow[i] ? 0.0f : -1e30f;

    const size_t RS = 3072;
    const bf16* qp0 = qkv + (size_t)(b * 2048 + q0 + l15) * RS + h * 64 + g * 8;
    const bf16* qp1 = qp0 + (size_t)64 * RS;
    bf16x8 aQ[2][2];
    aQ[0][0] = *(const bf16x8*)(qp0);
    aQ[0][1] = *(const bf16x8*)(qp0 + 32);
    aQ[1][0] = *(const bf16x8*)(qp1);
    aQ[1][1] = *(const bf16x8*)(qp1 + 32);

    const bf16* kbase = qkv + (size_t)(b * 2048) * RS + 1024 + h * 64;
    const bf16* vbase = vtg + (size_t)bh * (64 * 2048);

    // staging: 512 x 16B slots per matrix; thread t round r -> elem t*8+r*2048
    const int e0 = t * 8;
    int srow[2], scol[2];
#pragma unroll
    for (int r = 0; r < 2; ++r) {
        int e   = e0 + r * 2048;
        int row = e >> 6;
        int cb  = (e >> 3) & 7;
        srow[r] = row;
        scol[r] = ((cb ^ (row & 7)) * 8);   // inverse-swizzled global source
    }

    const int rb0 = ((g)     ^ (l15 & 7)) * 8;   // swizzled LDS read offsets
    const int rb1 = ((4 + g) ^ (l15 & 7)) * 8;

    const f32x4 z = {0.f, 0.f, 0.f, 0.f};
    f32x4 o0[4] = {z, z, z, z}, o1[4] = {z, z, z, z};
    f32x4 lacc0 = z, lacc1 = z;

    bf16x8 ones;
#pragma unroll
    for (int j = 0; j < 8; ++j) ones[j] = (bf16)1.0f;

    // ---- prologue: stage chunk 0 into buffers[0] ----
#pragma unroll
    for (int r = 0; r < 2; ++r) {
        GLOAD_LDS(kbase + (size_t)srow[r] * RS + scol[r],   &Ks[0][e0 + r * 2048]);
        GLOAD_LDS(vbase + (size_t)srow[r] * 2048 + scol[r], &Vt[0][e0 + r * 2048]);
    }
    asm volatile("s_waitcnt vmcnt(0)" ::: "memory");
    __syncthreads();

    for (int i = 0; i < 32; ++i) {
        const int kc  = i * 64;
        const int buf = i & 1;

        // ---- async prefetch chunk i+1 into the other buffers ----
        if (i + 1 < 32) {
#pragma unroll
            for (int r = 0; r < 2; ++r) {
                GLOAD_LDS(kbase + (size_t)(kc + 64 + srow[r]) * RS + scol[r],
                          &Ks[buf ^ 1][e0 + r * 2048]);
                GLOAD_LDS(vbase + (size_t)srow[r] * 2048 + kc + 64 + scol[r],
                          &Vt[buf ^ 1][e0 + r * 2048]);
            }
        }

        float mb[4];
#pragma unroll
        for (int kt = 0; kt < 4; ++kt) mb[kt] = mneg[kc + kt * 16 + l15];

        // ---- K fragments, shared by both q-tiles ----
        bf16x8 bk[4][2];
#pragma unroll
        for (int kt = 0; kt < 4; ++kt) {
            const bf16* kr = &Ks[buf][(kt * 16 + l15) * 64];
            bk[kt][0] = *(const bf16x8*)(kr + rb0);
            bk[kt][1] = *(const bf16x8*)(kr + rb1);
        }

        // ---- tile 0: S (mask in C-init), exp, P roundtrip ----
        f32x4 S[4];
#pragma unroll
        for (int kt = 0; kt < 4; ++kt) {
            f32x4 ini = {mb[kt], mb[kt], mb[kt], mb[kt]};
            S[kt] = MFMA16(aQ[0][0], bk[kt][0], ini);
            S[kt] = MFMA16(aQ[0][1], bk[kt][1], S[kt]);
        }
#pragma unroll
        for (int kt = 0; kt < 4; ++kt)
#pragma unroll
            for (int r = 0; r < 4; ++r)
                Ps[wave][(g * 4 + r) * 88 + kt * 16 + l15] =
                    (bf16)__builtin_amdgcn_exp2f(S[kt][r]);
        asm volatile("s_waitcnt lgkmcnt(0)" ::: "memory");
        const bf16x8 aP00 = *(const bf16x8*)(&Ps[wave][l15 * 88 + g * 8]);
        const bf16x8 aP01 = *(const bf16x8*)(&Ps[wave][l15 * 88 + 32 + g * 8]);
        asm volatile("s_waitcnt lgkmcnt(0)" ::: "memory");  // aP0 in regs; Ps reusable

        // ---- tile 1: S (reusing bk) ----
#pragma unroll
        for (int kt = 0; kt < 4; ++kt) {
            f32x4 ini = {mb[kt], mb[kt], mb[kt], mb[kt]};
            S[kt] = MFMA16(aQ[1][0], bk[kt][0], ini);
            S[kt] = MFMA16(aQ[1][1], bk[kt][1], S[kt]);
        }

        // ---- V fragments, read ONCE, shared by both q-tiles ----
        bf16x8 bv[4][2];
#pragma unroll
        for (int dt = 0; dt < 4; ++dt) {
            const bf16* vr = &Vt[buf][(dt * 16 + l15) * 64];
            bv[dt][0] = *(const bf16x8*)(vr + rb0);
            bv[dt][1] = *(const bf16x8*)(vr + rb1);
        }

#pragma unroll
        for (int kt = 0; kt < 4; ++kt)
#pragma unroll
            for (int r = 0; r < 4; ++r)
                Ps[wave][(g * 4 + r) * 88 + kt * 16 + l15] =
                    (bf16)__builtin_amdgcn_exp2f(S[kt][r]);

        // ---- tile 0 accumulate (overlaps tile-1 P roundtrip) ----
        lacc0 = MFMA16(aP00, ones, lacc0);
        lacc0 = MFMA16(aP01, ones, lacc0);
#pragma unroll
        for (int dt = 0; dt < 4; ++dt) {
            o0[dt] = MFMA16(aP00, bv[dt][0], o0[dt]);
            o0[dt] = MFMA16(aP01, bv[dt][1], o0[dt]);
        }
        asm volatile("s_waitcnt lgkmcnt(0)" ::: "memory");  // P1 committed
        const bf16x8 aP10 = *(const bf16x8*)(&Ps[wave][l15 * 88 + g * 8]);
        const bf16x8 aP11 = *(const bf16x8*)(&Ps[wave][l15 * 88 + 32 + g * 8]);

        // ---- tile 1 accumulate ----
        lacc1 = MFMA16(aP10, ones, lacc1);
        lacc1 = MFMA16(aP11, ones, lacc1);
#pragma unroll
        for (int dt = 0; dt < 4; ++dt) {
            o1[dt] = MFMA16(aP10, bv[dt][0], o1[dt]);
            o1[dt] = MFMA16(aP11, bv[dt][1], o1[dt]);
        }

        asm volatile("s_waitcnt vmcnt(0)" ::: "memory");  // prefetch landed
        __syncthreads();   // single barrier: buf^1 published, buf reads done
    }

    // ---- normalize + store both tiles ----
    float inv0[4], inv1[4];
#pragma unroll
    for (int r = 0; r < 4; ++r) {
        inv0[r] = 1.0f / fmaxf(lacc0[r], 1e-30f);
        inv1[r] = 1.0f / fmaxf(lacc1[r], 1e-30f);
    }
#pragma unroll
    for (int nt = 0; nt < 4; ++nt) {
#pragma unroll
        for (int r = 0; r < 4; ++r) {
            int d = nt * 16 + l15;
            int row0 = q0 + g * 4 + r;
            O[(size_t)(b * 2048 + row0) * 1024 + h * 64 + d] = (bf16)(o0[nt][r] * inv0[r]);
            O[(size_t)(b * 2048 + row0 + 64) * 1024 + h * 64 + d] = (bf16)(o1[nt][r] * inv1[r]);
        }
    }
}

// ---------------------------------------------------------------------------
extern "C" void kernel_launch(void* const* d_in, const int* in_sizes, int n_in,
                              void* d_out, int out_size, void* d_ws, size_t ws_size,
                              hipStream_t stream)
{
    const float* x     = (const float*)d_in[0];
    const int*   mask  = (const int*)d_in[1];
    const float* w_qkv = (const float*)d_in[2];
    const float* b_qkv = (const float*)d_in[3];
    const float* w_out = (const float*)d_in[4];
    const float* b_out = (const float*)d_in[5];
    float* out = (float*)d_out;

    char* ws = (char*)d_ws;
    bf16* qkvb  = (bf16*)(ws);                 // 48 MiB: [8192][3072]
    bf16* Obuf  = (bf16*)(ws + 50331648);      // 16 MiB: [8192][1024]
    bf16* xb    = (bf16*)(ws + 67108864);      // 16 MiB: [8192][1024]
    bf16* wqkvT = (bf16*)(ws + 83886080);      //  6 MiB: [3072][1024]
    bf16* woutT = (bf16*)(ws + 90177536);      //  2 MiB: [1024][1024]
    // VtG aliases xb: xb's last reader is the qkv GEMM, vtrans runs after it.
    bf16* vtg   = xb;                          // 16 MiB: [64 bh][64 d][2048 n]

    cvt_f32_bf16<<<dim3(8192), 256, 0, stream>>>(x, xb, 2097152);
    transpose_f32_bf16<<<dim3(48, 16), 256, 0, stream>>>(w_qkv, wqkvT, 1024, 3072,
                                                         1024, QSCALE);
    transpose_f32_bf16<<<dim3(16, 16), 256, 0, stream>>>(w_out, woutT, 1024, 1024,
                                                         0, 1.0f);
    gemm_bias_kernel<bf16><<<dim3(24, 64), 256, 0, stream>>>(
        xb, wqkvT, b_qkv, qkvb, 8192, 3072, 1024, 1024, QSCALE);
    vtrans_kernel<<<dim3(32, 64), 256, 0, stream>>>(qkvb, vtg);
    attn_kernel<<<dim3(1024), 256, 0, stream>>>(qkvb, vtg, mask, Obuf);
    gemm_bias_kernel<float><<<dim3(8, 64), 256, 0, stream>>>(
        Obuf, woutT, b_out, out, 8192, 1024, 1024, 0, 1.0f);
}